// Round 6
// baseline (57.897 us; speedup 1.0000x reference)
//
#include <hip/hip_runtime.h>

#define NB 524288
#define NC 32
#define EPSV 1e-4f
#define DTB 0.12f      // DT * BETA
#define CLAMPV 3.0f
#define NSTEPS 4

typedef float f32x2 __attribute__((ext_vector_type(2)));

__device__ __forceinline__ f32x2 pk_fma(f32x2 a, f32x2 b, f32x2 c) {
    return __builtin_elementwise_fma(a, b, c);
}

__global__ __launch_bounds__(256, 8) void pm_kernel(
    const float* __restrict__ z_in,
    const float* __restrict__ centers,
    const float* __restrict__ mus,
    float* __restrict__ out)
{
    const int i = blockIdx.x * 256 + threadIdx.x;

    const float4* zp = (const float4*)z_in;
    float4 a0 = zp[(size_t)i * 2], a1 = zp[(size_t)i * 2 + 1];
    f32x2 z[4] = {{a0.x, a0.y}, {a0.z, a0.w}, {a1.x, a1.y}, {a1.z, a1.w}};

    // Wave-uniform center reads -> s_load into SGPR pairs.
    const f32x2* cp = (const f32x2*)centers;

    // bb[c] = |c|^2 + EPS (uniform; compiler hoists to SGPR via readfirstlane)
    float bb[NC];
    #pragma unroll
    for (int c = 0; c < NC; ++c) {
        f32x2 q = cp[c * 4 + 0] * cp[c * 4 + 0];
        q = pk_fma(cp[c * 4 + 1], cp[c * 4 + 1], q);
        q = pk_fma(cp[c * 4 + 2], cp[c * 4 + 2], q);
        q = pk_fma(cp[c * 4 + 3], cp[c * 4 + 3], q);
        bb[c] = q.x + q.y + EPSV;
    }

    #pragma unroll 1
    for (int s = 0; s < NSTEPS; ++s) {
        // zz = |z|^2
        f32x2 q = z[0] * z[0];
        q = pk_fma(z[1], z[1], q);
        q = pk_fma(z[2], z[2], q);
        q = pk_fma(z[3], z[3], q);
        float zz = q.x + q.y;

        float n = 1.0f;
        float sw = 0.0f;
        f32x2 gc[4] = {{0.f,0.f},{0.f,0.f},{0.f,0.f},{0.f,0.f}};

        #pragma unroll
        for (int c = 0; c < NC; ++c) {
            const f32x2 c0 = cp[c * 4 + 0], c1 = cp[c * 4 + 1];
            const f32x2 c2 = cp[c * 4 + 2], c3 = cp[c * 4 + 3];

            // r2 = zz + |c|^2 + eps - 2*dot(z, c)
            f32x2 p = z[0] * c0;
            p = pk_fma(z[1], c1, p);
            p = pk_fma(z[2], c2, p);
            p = pk_fma(z[3], c3, p);
            float dot = p.x + p.y;
            float r2 = fmaf(-2.0f, dot, zz + bb[c]);

            float rinv = __builtin_amdgcn_rsqf(r2);  // v_rsq_f32
            float w    = mus[c] * rinv;              // mu / r
            n += w;
            float w3   = (w * rinv) * rinv;          // mu / (r * r2)
            sw += w3;
            f32x2 w3v = {w3, w3};
            gc[0] = pk_fma(w3v, c0, gc[0]);
            gc[1] = pk_fma(w3v, c1, gc[1]);
            gc[2] = pk_fma(w3v, c2, gc[2]);
            gc[3] = pk_fma(w3v, c3, gc[3]);
        }

        // g = gc - sw * z ;  z = clamp(z + (DTB/n) * g)
        float scale = DTB * __builtin_amdgcn_rcpf(n);  // v_rcp_f32
        f32x2 nsw = {-sw, -sw};
        f32x2 sv  = {scale, scale};
        const f32x2 lo = {-CLAMPV, -CLAMPV}, hi = {CLAMPV, CLAMPV};
        #pragma unroll
        for (int k = 0; k < 4; ++k) {
            f32x2 g = pk_fma(nsw, z[k], gc[k]);
            z[k] = pk_fma(sv, g, z[k]);
            z[k] = __builtin_elementwise_min(__builtin_elementwise_max(z[k], lo), hi);
        }
    }

    float4 o0 = {z[0].x, z[0].y, z[1].x, z[1].y};
    float4 o1 = {z[2].x, z[2].y, z[3].x, z[3].y};
    float4* op = (float4*)out;
    op[(size_t)i * 2]     = o0;
    op[(size_t)i * 2 + 1] = o1;
}

extern "C" void kernel_launch(void* const* d_in, const int* in_sizes, int n_in,
                              void* d_out, int out_size, void* d_ws, size_t ws_size,
                              hipStream_t stream) {
    const float* z       = (const float*)d_in[0];
    const float* centers = (const float*)d_in[1];
    const float* mus     = (const float*)d_in[2];
    float* out           = (float*)d_out;

    dim3 block(256);
    dim3 grid(NB / 256);   // 2048 blocks, 1 point per thread
    pm_kernel<<<grid, block, 0, stream>>>(z, centers, mus, out);
}